// Round 12
// baseline (92.154 us; speedup 1.0000x reference)
//
#include <hip/hip_runtime.h>
#include <math.h>

#define WIN 16   // +/- phoneme-index window (rounds 1/5/6/8/11 verified)
#define FPW 8    // frames per wave
#define NW  4    // waves per block (independent; no block-level sync)
#define CHK 64   // weight-table chunk

// Kernel 1: per-batch inclusive cumsum of durations (double precision scan),
// centers c[b,n] = cumsum(dur)[b,n] - 0.5*dur[b,n]   (verbatim)
__global__ void centers_kernel(const float* __restrict__ dur,
                               float* __restrict__ c, int N) {
    extern __shared__ double s[];
    int b = blockIdx.x;
    int n = threadIdx.x;
    float d = (n < N) ? dur[(size_t)b * N + n] : 0.0f;
    if (n < N) s[n] = (double)d;
    __syncthreads();
    for (int off = 1; off < N; off <<= 1) {
        double v = (n >= off && n < N) ? s[n - off] : 0.0;
        __syncthreads();
        if (n < N) s[n] += v;
        __syncthreads();
    }
    if (n < N) c[(size_t)b * N + n] = (float)(s[n] - 0.5 * (double)d);
}

// Kernel 1.5: per-frame nearest-center index (lower_bound + adjust, verbatim
// predicate/rounding from the verified R11 prologue). Massive TLP hides the
// dependent binary-search chain; removes the N-scan from the main kernel.
__global__ __launch_bounds__(256) void bounds_kernel(
    const float* __restrict__ c, const int* __restrict__ lens,
    int* __restrict__ jn, int N, int T) {
    int gt = blockIdx.x * 256 + threadIdx.x;   // over B*T
    int b = gt / T;
    int t = gt - b * T;
    const float* cb = c + (size_t)b * N;
    int L = lens[b];
    if (L < 1) L = 1;
    if (L > N) L = N;
    float tf = (float)t;
    int lo = 0, hi = L;
    while (lo < hi) {
        int mid = (lo + hi) >> 1;
        if (cb[mid] < tf) lo = mid + 1; else hi = mid;
    }
    int j = lo;
    if (j >= L) j = L - 1;
    float cj   = cb[j];
    float cjm1 = cb[(j > 0) ? (j - 1) : 0];
    if (j > 0 && (tf - cjm1) < (cj - tf)) j--;
    jn[gt] = j;
}

// Kernel 2: 4 independent waves per block; each wave = 8 frames x HALF a row
// (256 cols). acc drops to 32 VGPRs; __launch_bounds__(256,8) forces <=64
// VGPR => 8 waves/SIMD occupancy cap (2x round-11). Math verbatim round-11
// (direct max = nearest-center score, verified bit-identical; softmax
// sum-reduce, full-wave shfl gather, LDS tbl broadcast, ascending-k fma).
__global__ __launch_bounds__(256, 8) void upsample_half(
    const float* __restrict__ x,    // [B,N,H]
    const int* __restrict__ lens,   // [B]
    const float* __restrict__ c,    // [B,N]
    const int* __restrict__ jn,     // [B,T] nearest-center index
    float* __restrict__ out,        // [B,T,H]
    int B, int N, int H, int T) {
    __shared__ float tbl[NW][CHK * FPW];   // per-wave weights: 8 per k (8 KB)

    int nwg = gridDim.x;
    int bid = blockIdx.x;
    if ((nwg & 7) == 0) {                  // XCD-bijective swizzle
        int cpx = nwg >> 3;
        bid = (bid & 7) * cpx + (bid >> 3);
    }
    int wave = threadIdx.x >> 6;
    int lane = threadIdx.x & 63;

    int tilesPerB = T >> 4;                // 16 frames per block-tile
    int b    = bid / tilesPerB;
    int tile = bid - b * tilesPerB;
    int octet = wave >> 1;                 // which 8-frame group
    int half  = wave & 1;                  // which 256-col half
    int t0 = tile * 16 + octet * 8;

    const float* cb = c + (size_t)b * N;
    int L = lens[b];
    if (L < 1) L = 1;
    if (L > N) L = N;

    float tf[FPW];
    #pragma unroll
    for (int f = 0; f < FPW; ++f) tf[f] = (float)(t0 + f);

    // ---- precomputed nearest index; windows + direct max (verbatim R11) ----
    const int* jb = jn + (size_t)b * T + t0;
    int a[FPW], e[FPW];
    float m_[FPW];
    #pragma unroll
    for (int f = 0; f < FPW; ++f) {
        int j = jb[f];
        int af = j - WIN; if (af < 0) af = 0;
        int ef = j + WIN; if (ef > L - 1) ef = L - 1;
        a[f] = af; e[f] = ef;
        float dm = tf[f] - cb[j];
        m_[f] = -0.5f * dm * dm;           // max of windowed scores
    }

    // ---- per-frame softmax (verbatim; lane k holds w_k) ----
    float w[FPW];
    #pragma unroll
    for (int f = 0; f < FPW; ++f) {
        int K = e[f] - a[f] + 1;
        float ev = 0.0f;
        if (lane < K) {
            float d  = tf[f] - cb[a[f] + lane];
            float sc = -0.5f * d * d;
            ev = __expf(sc - m_[f]);
        }
        float sum = ev;
        #pragma unroll
        for (int off = 32; off; off >>= 1) sum += __shfl_xor(sum, off);
        w[f] = ev / sum;                   // lanes >= K hold exactly 0.0f
    }

    int n0   = a[0];                       // per-octet union (j monotone)
    int span = e[FPW - 1] - n0 + 1;

    const float4* rbase =
        (const float4*)(x + ((size_t)b * N + n0) * (size_t)H + half * 256);
    int H4 = H >> 2;                       // 128 float4s per full row

    float4 acc[FPW];
    #pragma unroll
    for (int f = 0; f < FPW; ++f) acc[f] = make_float4(0.f, 0.f, 0.f, 0.f);

    for (int kb = 0; kb < span; kb += CHK) {
        int klen = span - kb; if (klen > CHK) klen = CHK;

        // per-wave weight table (full-wave shfls; only the write predicated)
        int nn = kb + lane;
        float wv[FPW];
        #pragma unroll
        for (int f = 0; f < FPW; ++f) {
            unsigned q = (unsigned)(nn + n0 - a[f]);
            float g = __shfl(w[f], (int)(q & 63u));
            wv[f] = (q < 64u) ? g : 0.0f;
        }
        if (lane < klen) {
            float4* tw = (float4*)&tbl[wave][lane * FPW];
            tw[0] = make_float4(wv[0], wv[1], wv[2], wv[3]);
            tw[1] = make_float4(wv[4], wv[5], wv[6], wv[7]);
        }

        // ---- depth-2 pipelined direct-from-L2 fma loop (ascending k) ----
        const float4* rp = rbase + (size_t)kb * H4;
        float4 va0, va1;
        va0 = rp[lane];
        if (klen > 1) va1 = rp[H4 + lane];
        for (int k = 0; k < klen; ++k) {
            float4 na;
            if (k + 2 < klen) na = rp[(size_t)(k + 2) * H4 + lane];
            const float4* twk = (const float4*)&tbl[wave][k * FPW];  // broadcast
            float4 wlo = twk[0], whi = twk[1];
            const float wk[FPW] = { wlo.x, wlo.y, wlo.z, wlo.w,
                                    whi.x, whi.y, whi.z, whi.w };
            #pragma unroll
            for (int f = 0; f < FPW; ++f) {
                acc[f].x = fmaf(wk[f], va0.x, acc[f].x);
                acc[f].y = fmaf(wk[f], va0.y, acc[f].y);
                acc[f].z = fmaf(wk[f], va0.z, acc[f].z);
                acc[f].w = fmaf(wk[f], va0.w, acc[f].w);
            }
            va0 = va1;
            va1 = na;
        }
    }

    // ---- store the wave's 8 half-rows ----
    float* obase = out + ((size_t)b * T + t0) * (size_t)H + half * 256;
    #pragma unroll
    for (int f = 0; f < FPW; ++f)
        ((float4*)(obase + (size_t)f * H))[lane] = acc[f];
}

extern "C" void kernel_launch(void* const* d_in, const int* in_sizes, int n_in,
                              void* d_out, int out_size, void* d_ws, size_t ws_size,
                              hipStream_t stream) {
    const float* x    = (const float*)d_in[0];  // [B,N,H] f32
    const int*   lens = (const int*)d_in[1];    // [B] int
    const float* dur  = (const float*)d_in[2];  // [B,N] f32

    int B  = in_sizes[1];
    int BN = in_sizes[2];
    int N  = BN / B;
    int H  = in_sizes[0] / BN;
    int T  = out_size / (B * H);

    float* c  = (float*)d_ws;                   // B*N floats
    int*   jnr = (int*)((char*)d_ws + (size_t)B * N * sizeof(float));  // B*T ints

    centers_kernel<<<B, N, N * sizeof(double), stream>>>(dur, c, N);
    bounds_kernel<<<(B * T) / 256, 256, 0, stream>>>(c, lens, jnr, N, T);

    int blocks = (B * T) / 16;                  // 16 frames per block-tile
    upsample_half<<<blocks, 256, 0, stream>>>(x, lens, c, jnr, (float*)d_out,
                                              B, N, H, T);
}

// Round 13
// 56.209 us; speedup vs baseline: 1.6395x; 1.6395x over previous
//
#include <hip/hip_runtime.h>
#include <math.h>

#define WIN 16   // +/- phoneme-index window (rounds 1/5/6/8/11/12 verified)
#define FPW 8    // frames per wave
#define NW  4    // waves per block
#define FPB (FPW * NW)   // 32 frames per block
#define CH  16   // staged rows per chunk (32 KB)

#define AS1 __attribute__((address_space(1)))
#define AS3 __attribute__((address_space(3)))

// Kernel 1: per-batch inclusive cumsum of durations (double precision scan),
// centers c[b,n] = cumsum(dur)[b,n] - 0.5*dur[b,n]   (verbatim)
__global__ void centers_kernel(const float* __restrict__ dur,
                               float* __restrict__ c, int N) {
    extern __shared__ double s[];
    int b = blockIdx.x;
    int n = threadIdx.x;
    float d = (n < N) ? dur[(size_t)b * N + n] : 0.0f;
    if (n < N) s[n] = (double)d;
    __syncthreads();
    for (int off = 1; off < N; off <<= 1) {
        double v = (n >= off && n < N) ? s[n - off] : 0.0;
        __syncthreads();
        if (n < N) s[n] += v;
        __syncthreads();
    }
    if (n < N) c[(size_t)b * N + n] = (float)(s[n] - 0.5 * (double)d);
}

// Kernel 1.5: per-frame nearest index (verbatim R12 search, verified) plus
// the softmax denominator: inv = 1/sum_{k in window} exp(sc_k - m), with
// m = nearest-center score (verified max). Serial sum ~ tree sum +-1 ulp.
__global__ __launch_bounds__(256) void bounds_kernel(
    const float* __restrict__ c, const int* __restrict__ lens,
    int* __restrict__ jn, float* __restrict__ inv, int N, int T) {
    int gt = blockIdx.x * 256 + threadIdx.x;   // over B*T
    int b = gt / T;
    int t = gt - b * T;
    const float* cb = c + (size_t)b * N;
    int L = lens[b];
    if (L < 1) L = 1;
    if (L > N) L = N;
    float tf = (float)t;
    int lo = 0, hi = L;
    while (lo < hi) {
        int mid = (lo + hi) >> 1;
        if (cb[mid] < tf) lo = mid + 1; else hi = mid;
    }
    int j = lo;
    if (j >= L) j = L - 1;
    float cj   = cb[j];
    float cjm1 = cb[(j > 0) ? (j - 1) : 0];
    if (j > 0 && (tf - cjm1) < (cj - tf)) j--;
    jn[gt] = j;
    float dm = tf - cb[j];
    float m = -0.5f * dm * dm;                 // max of windowed scores
    int a = j - WIN; if (a < 0) a = 0;
    int e = j + WIN; if (e > L - 1) e = L - 1;
    float sum = 0.0f;
    for (int k = a; k <= e; ++k) {
        float d  = tf - cb[k];
        float sc = -0.5f * d * d;
        sum += __expf(sc - m);
    }
    inv[gt] = 1.0f / sum;
}

// Kernel 2: R8's verified staging structure (4 waves x 8 frames, CH=16
// global_load_lds chunks, 2 barriers/chunk, ascending-k fma). DS-pipe diet:
// no LDS weight table, no softmax/gather shfls — each lane computes its 8
// weights directly (1 coalesced c-load + 8 exps), per-k broadcast via
// readlane (SGPR-operand fma). Weights: same expression/rounding as R8
// except 1/sum from bounds_kernel (serial sum, ~1e-7 rel drift).
__global__ __launch_bounds__(256, 4) void upsample_rl(
    const float* __restrict__ x,    // [B,N,H]
    const int* __restrict__ lens,   // [B]
    const float* __restrict__ c,    // [B,N]
    const int* __restrict__ jn,     // [B,T] nearest index
    const float* __restrict__ inv,  // [B,T] softmax 1/sum
    float* __restrict__ out,        // [B,T,H]
    int B, int N, int H, int T) {
    __shared__ float rows[CH][512];        // 32 KB staged input rows (H=512)
    __shared__ int   bnd[2];               // block union window [n0, nEnd]

    int nwg = gridDim.x;
    int bid = blockIdx.x;
    if ((nwg & 7) == 0) {                  // XCD-bijective swizzle
        int cpx = nwg >> 3;
        bid = (bid & 7) * cpx + (bid >> 3);
    }
    int wave = threadIdx.x >> 6;
    int lane = threadIdx.x & 63;

    int tilesPerB = T / FPB;
    int b   = bid / tilesPerB;
    int t0  = (bid - b * tilesPerB) * FPB + wave * FPW;

    const float* cb = c + (size_t)b * N;
    int L = lens[b];
    if (L < 1) L = 1;
    if (L > N) L = N;

    // ---- per-frame window params from precomputed nearest index ----
    const int*   jb  = jn  + (size_t)b * T + t0;
    const float* ivb = inv + (size_t)b * T + t0;
    float tf[FPW], m_[FPW], iv[FPW];
    int a[FPW], e[FPW];
    #pragma unroll
    for (int f = 0; f < FPW; ++f) {
        tf[f] = (float)(t0 + f);
        int j = jb[f];
        int af = j - WIN; if (af < 0) af = 0;
        int ef = j + WIN; if (ef > L - 1) ef = L - 1;
        a[f] = af; e[f] = ef;
        float dm = tf[f] - cb[j];
        m_[f] = -0.5f * dm * dm;           // max of windowed scores
        iv[f] = ivb[f];
    }

    // block union window: nearest index monotone in t => [w0.a[0], w3.e[7]]
    if (wave == 0 && lane == 0) bnd[0] = a[0];
    if (wave == NW - 1 && lane == 0) bnd[1] = e[FPW - 1];
    __syncthreads();
    int n0   = bnd[0];
    int span = bnd[1] - n0 + 1;

    const float* gbase = x + ((size_t)b * N + n0) * (size_t)H;

    float4 acc[FPW][2];
    #pragma unroll
    for (int f = 0; f < FPW; ++f) {
        acc[f][0] = make_float4(0.f, 0.f, 0.f, 0.f);
        acc[f][1] = make_float4(0.f, 0.f, 0.f, 0.f);
    }

    for (int kb = 0; kb < span; kb += CH) {
        int klen = span - kb; if (klen > CH) klen = CH;

        // ---- async stage (verbatim R8): linear dest == linear read ----
        for (int r = wave; r < klen; r += NW) {
            const char* g = (const char*)(gbase + (size_t)(kb + r) * H);
            __builtin_amdgcn_global_load_lds(
                (const AS1 void*)(g + lane * 16),
                (AS3 void*)&rows[r][0], 16, 0, 0);
            __builtin_amdgcn_global_load_lds(
                (const AS1 void*)(g + 1024 + lane * 16),
                (AS3 void*)&rows[r][256], 16, 0, 0);
        }

        // ---- per-lane weights for union index kb+lane (overlaps DMA):
        //      1 coalesced c load + 8 exps; out-of-window => exact 0.0f ----
        int nidx = n0 + kb + lane;
        int ci = nidx; if (ci > L - 1) ci = L - 1;
        float cv = cb[ci];
        float wv[FPW];
        #pragma unroll
        for (int f = 0; f < FPW; ++f) {
            float d  = tf[f] - cv;
            float sc = -0.5f * d * d;
            float wval = __expf(sc - m_[f]) * iv[f];
            wv[f] = (nidx >= a[f] && nidx <= e[f]) ? wval : 0.0f;
        }
        __syncthreads();                   // DMA drained; rows resident

        // ---- fma from LDS, ascending k; weights via readlane (VALU) ----
        for (int k = 0; k < klen; ++k) {
            float wk[FPW];
            #pragma unroll
            for (int f = 0; f < FPW; ++f)
                wk[f] = __uint_as_float(
                    __builtin_amdgcn_readlane(__float_as_uint(wv[f]), k));
            const float4* row = (const float4*)rows[k];
            float4 va = row[lane];
            float4 vb = row[64 + lane];
            #pragma unroll
            for (int f = 0; f < FPW; ++f) {
                acc[f][0].x = fmaf(wk[f], va.x, acc[f][0].x);
                acc[f][0].y = fmaf(wk[f], va.y, acc[f][0].y);
                acc[f][0].z = fmaf(wk[f], va.z, acc[f][0].z);
                acc[f][0].w = fmaf(wk[f], va.w, acc[f][0].w);
                acc[f][1].x = fmaf(wk[f], vb.x, acc[f][1].x);
                acc[f][1].y = fmaf(wk[f], vb.y, acc[f][1].y);
                acc[f][1].z = fmaf(wk[f], vb.z, acc[f][1].z);
                acc[f][1].w = fmaf(wk[f], vb.w, acc[f][1].w);
            }
        }
        __syncthreads();                   // rows safe to overwrite
    }

    // ---- store the wave's 8 frames ----
    float* obase = out + ((size_t)b * T + t0) * (size_t)H;
    #pragma unroll
    for (int f = 0; f < FPW; ++f) {
        float4* o = (float4*)(obase + (size_t)f * H);
        o[lane]      = acc[f][0];
        o[64 + lane] = acc[f][1];
    }
}

extern "C" void kernel_launch(void* const* d_in, const int* in_sizes, int n_in,
                              void* d_out, int out_size, void* d_ws, size_t ws_size,
                              hipStream_t stream) {
    const float* x    = (const float*)d_in[0];  // [B,N,H] f32
    const int*   lens = (const int*)d_in[1];    // [B] int
    const float* dur  = (const float*)d_in[2];  // [B,N] f32

    int B  = in_sizes[1];
    int BN = in_sizes[2];
    int N  = BN / B;
    int H  = in_sizes[0] / BN;
    int T  = out_size / (B * H);

    float* c   = (float*)d_ws;                                        // B*N f32
    int*   jnr = (int*)((char*)d_ws + (size_t)B * N * sizeof(float)); // B*T i32
    float* ivr = (float*)((char*)jnr + (size_t)B * T * sizeof(int));  // B*T f32

    centers_kernel<<<B, N, N * sizeof(double), stream>>>(dur, c, N);
    bounds_kernel<<<(B * T) / 256, 256, 0, stream>>>(c, lens, jnr, ivr, N, T);

    int blocks = (B * T) / FPB;             // 32 frames per block
    upsample_rl<<<blocks, 256, 0, stream>>>(x, lens, c, jnr, ivr,
                                            (float*)d_out, B, N, H, T);
}